// Round 13
// baseline (2411.698 us; speedup 1.0000x reference)
//
#include <hip/hip_runtime.h>

// ---------------------------------------------------------------------------
// self_LSTM_sparse_attn — MI355X persistent-kernel, round 23.
//
// R22 (1623us, session best) is the R18 skeleton. R23 removes the S2
// barrier — the last untouched structural latency on the step loop:
//   (1) red2/psum parity-DOUBLE-BUFFERED ([2][..], LDS 43->60KB) — kills
//       S2's buffer-protection role. Skew is bounded by S1 to one
//       iteration; buffer-p reads at step i complete before any wave can
//       pass S1(i+1), i.e. before the earliest step-i+2 write of buffer p.
//       (512-thr + 60KB -> 2 WG/CU target -> VGPR cap 128 > our ~88; the
//       64-VGPR spill trap was 1024-thr-specific.)
//   (2) flag-gated stores CONSOLIDATED into wave 0: it stores mem AND psum
//       (tail is replicated; wave 0 has tanh(ho)*wt), then a wave-local
//       s_waitcnt vmcnt(0) orders its own stores, then lane 0 publishes
//       flag[g]. All asm volatile + memory clobber => program-ordered.
//       No useful VMEM in flight at the drain (R20/R21 FIFO trap N/A).
//       mseq -> wave 1, plain store (out_gemm gated by kernel boundary,
//       unchanged). Tail replicas 3 -> 2.
// Flag semantics byte-equivalent: flag=i+1 only after g's mem[i+1] AND
// psum[i+1] are at LIC. Critical loop loses one barrier release + all-wave
// drain per step; flag publishes earlier to all consumers.
//
// Session map: weight delivery LDS broadcast optimal (1795 > 2900 SMEM >
// 4020 VMEM); 1024-thr arc dead (64-VGPR cap, spills); fp16 h-state dead
// (absmax 4.9); split producer wait dead (vmcnt FIFO); tail gating WIN.
//
// Carried invariants (R5-R8-verified): cross-WG data write-once per step;
// cross-WG stores direct to LIC via sc0 sc1 (no fences anywhere); flag[g]
// stored only after g's plane stores drained; per-wave producer wait (wave
// kqu polls flag[32kqu+(b&31)], covering its psum slots AND mem dims).
// Algorithm (R2-R8-verified): s_h cancels in attention weights; w <=4-sparse;
// WG g owns h dims {2g,2g+1}; mem[i] == h_out(i-1); incremental top-5 with
// register-carried gather values (qa,qb).
// ---------------------------------------------------------------------------

#define T_N 256
#define B_N 64
#define I_N 256
#define H_N 512
#define C_N 64
#define EPSF 1e-7f

typedef float v4f __attribute__((ext_vector_type(4)));
typedef float v2f __attribute__((ext_vector_type(2)));

// ws layout (float offsets). Packed layouts: [..][k4][b][u] u=k&3.
#define XT4_F   0u          // [T][64][64][4]    x packed          (4,194,304)
#define MEM4_F  4194304u    // [T+1][128][64][4] h_out history     (8,421,376)
#define MSEQ4_F 12615680u   // [T][128][64][4]   m_seq             (8,388,608)
#define PSUM4_F 21004288u   // [T+1][64][64][4]  score partials, write-once (4,210,688)
#define FCWT_F  25214976u   // [2H][C] fc_w transposed             (65,536)
#define FLAG_F  25280512u   // [256] arrival flags, packed u32     (256)
#define TOT_F   25280768u

__device__ __forceinline__ float sigf(float x) { return 1.0f / (1.0f + expf(-x)); }

// direct-to-LIC (coherence point) ops — no fences needed anywhere.
__device__ __forceinline__ void st_lic_f32(float* p, float v) {
  asm volatile("global_store_dword %0, %1, off sc0 sc1" :: "v"(p), "v"(v) : "memory");
}
__device__ __forceinline__ void st_lic_f32x2(float* p, v2f v) {
  asm volatile("global_store_dwordx2 %0, %1, off sc0 sc1" :: "v"(p), "v"(v) : "memory");
}
__device__ __forceinline__ void st_lic_u32(unsigned* p, unsigned v) {
  asm volatile("global_store_dword %0, %1, off sc0 sc1" :: "v"(p), "v"(v) : "memory");
}
__device__ __forceinline__ unsigned ld_lic_u32(const unsigned* p) {
  unsigned r;
  asm volatile("global_load_dword %0, %1, off sc0 sc1\n\ts_waitcnt vmcnt(0)"
               : "=v"(r) : "v"(p) : "memory");
  return r;
}

// insert (s, a0, a1) into descending top-5; slots 0..3 carry values (qa,qb)
__device__ __forceinline__ void ins5v(float s, float a0, float a1,
    float& v0, float& v1, float& v2, float& v3, float& v4,
    float& qa0, float& qb0, float& qa1, float& qb1,
    float& qa2, float& qb2, float& qa3, float& qb3) {
  if (s > v4) {
    if (s > v0) {
      v4=v3; v3=v2; qa3=qa2; qb3=qb2; v2=v1; qa2=qa1; qb2=qb1;
      v1=v0; qa1=qa0; qb1=qb0; v0=s; qa0=a0; qb0=a1;
    } else if (s > v1) {
      v4=v3; v3=v2; qa3=qa2; qb3=qb2; v2=v1; qa2=qa1; qb2=qb1;
      v1=s; qa1=a0; qb1=a1;
    } else if (s > v2) {
      v4=v3; v3=v2; qa3=qa2; qb3=qb2; v2=s; qa2=a0; qb2=a1;
    } else if (s > v3) {
      v4=v3; v3=s; qa3=a0; qb3=a1;
    } else {
      v4=s;
    }
  }
}

__global__ void poison_k(float* out, int n) {
  int i = blockIdx.x * 256 + threadIdx.x;
  if (i < n) out[i] = __int_as_float(0x7fc00000);
}

// blocks 0..1023: x -> xT4 packed; blocks 1024..1039: fc_w -> fcwT[d][c]
__global__ void init_k(const float* __restrict__ x, const float* __restrict__ fc_w,
                       float* __restrict__ ws) {
  __shared__ float tile[64][65];
  const int blk = blockIdx.x, tid = threadIdx.x;
  if (blk < 1024) {
    const int t = blk >> 2, k0 = (blk & 3) * 64;
    for (int u = tid; u < 4096; u += 256) {
      int bb = u >> 6, kk = u & 63;
      tile[kk][bb] = x[((unsigned)t * 64u + bb) * 256u + k0 + kk];
    }
    __syncthreads();
    for (int u = tid; u < 4096; u += 256) {
      int kk = u >> 6, bb = u & 63;
      int k = k0 + kk;
      ws[XT4_F + (unsigned)t * 16384u + (unsigned)(k >> 2) * 256u
         + (unsigned)bb * 4u + (unsigned)(k & 3)] = tile[kk][bb];
    }
  } else {
    const int d0 = (blk - 1024) * 64;
    for (int u = tid; u < 4096; u += 256) {
      int cc = u >> 6, dd = u & 63;
      tile[dd][cc] = fc_w[(unsigned)cc * 1024u + d0 + dd];
    }
    __syncthreads();
    for (int u = tid; u < 4096; u += 256) {
      int dd = u >> 6, cc = u & 63;
      ws[FCWT_F + (unsigned)(d0 + dd) * 64u + cc] = tile[dd][cc];
    }
  }
}

__launch_bounds__(512, 1)
__global__ void lstm_main(const float* __restrict__ W_ih, const float* __restrict__ W_hh,
                          const float* __restrict__ b_ih, const float* __restrict__ b_hh,
                          const float* __restrict__ w_t, float* __restrict__ ws) {
  __shared__ float Wx[I_N][8];              // 8 KB  weight rows, LDS-resident
  __shared__ float Wh[H_N][8];              // 16 KB
  __shared__ float red2[2][8][4][B_N][2];   // 32 KB gate partials, parity-dbuf
  __shared__ float psum[2][8][B_N];         // 4 KB  score partials, parity-dbuf

  const int g = blockIdx.x;
  const int tid = threadIdx.x;
  const int b = tid & 63;
  const int kqu = __builtin_amdgcn_readfirstlane(tid >> 6);  // wave id 0..7

  unsigned int* flags = (unsigned int*)(ws + FLAG_F);

  // stage weights (resident all steps)
  for (int idx = tid; idx < 8 * I_N; idx += 512) {
    int rr = idx >> 8, k = idx & (I_N - 1);
    int grow = (rr >> 1) * H_N + 2 * g + (rr & 1);   // rr = gate*2 + jj
    Wx[k][rr] = W_ih[grow * I_N + k];
  }
  for (int idx = tid; idx < 8 * H_N; idx += 512) {
    int rr = idx >> 9, k = idx & (H_N - 1);
    int grow = (rr >> 1) * H_N + 2 * g + (rr & 1);
    Wh[k][rr] = W_hh[grow * H_N + k];
  }
  float bias_r[8];
  #pragma unroll
  for (int r = 0; r < 8; ++r) {
    int grow = (r >> 1) * H_N + 2 * g + (r & 1);
    bias_r[r] = b_ih[grow] + b_hh[grow];
  }
  const float wt20 = w_t[H_N + 2 * g];
  const float wt21 = w_t[H_N + 2 * g + 1];
  __syncthreads();

  // per-wave replicated state (bit-identical streams across tail waves 0..1)
  float cs0 = 0.0f, cs1 = 0.0f;                 // LSTM c-state
  float po0 = 0.0f, po1 = 0.0f;                 // ho(i-1) == mem[i] values (own dims)
  float v0 = -3e38f, v1 = -3e38f, v2 = -3e38f, v3 = -3e38f, v4 = -3e38f;
  float qa0 = 0, qb0 = 0, qa1 = 0, qb1 = 0, qa2 = 0, qb2 = 0, qa3 = 0, qb3 = 0;
  float mn = 3e38f;

  const unsigned hoff0 = (unsigned)(g >> 1) * 256u + (unsigned)b * 4u + (unsigned)((g & 1) * 2);

  // prologue: x-part of step 0's matvec (k-eighth per wave)
  float xacc[8];
  #pragma unroll
  for (int r = 0; r < 8; ++r) xacc[r] = 0.0f;
  {
    const v4f* xp = (const v4f*)(ws + XT4_F) + (unsigned)(kqu * 8) * 64u + b;
    v4f xv[8];
    #pragma unroll
    for (int j = 0; j < 8; ++j) xv[j] = xp[j * 64];
    #pragma unroll
    for (int j = 0; j < 8; ++j) {
      #pragma unroll
      for (int u = 0; u < 4; ++u) {
        float v = xv[j][u];
        const float* wr = &Wx[kqu * 32 + 4 * j + u][0];
        #pragma unroll
        for (int r = 0; r < 8; ++r) xacc[r] += v * wr[r];
      }
    }
  }

  for (int i = 0; i < T_N; ++i) {
    const int pr = i & 1;  // parity buffer for red2/psum

    // ---- S0: per-wave producer wait. Wave kqu's psum slots AND mem dims
    // are both written exactly by WGs [32kqu, 32kqu+32). Single poll BEFORE
    // any data loads (R21 lesson: vmcnt(0) covers only the flag load). ----
    if (i > 0) {
      const unsigned* fp = flags + (kqu * 32 + (b & 31));
      while (ld_lic_u32(fp) < (unsigned)i) __builtin_amdgcn_s_sleep(1);
    }

    // ---- Phase A: batched vector loads; weights broadcast from LDS ----
    v4f pv[8];
    {
      const v4f* pp = (const v4f*)(ws + PSUM4_F) + (unsigned)i * 4096u
                      + (unsigned)(kqu * 8) * 64u + b;
      #pragma unroll
      for (int j = 0; j < 8; ++j) pv[j] = pp[j * 64];
    }
    v4f hv[16];
    {
      const v4f* hp = (const v4f*)(ws + MEM4_F) + (unsigned)i * 8192u
                      + (unsigned)(kqu * 16) * 64u + b;  // mem[i] == h_out(i-1)
      #pragma unroll
      for (int j = 0; j < 16; ++j) hv[j] = hp[j * 64];
    }
    float ps = 0.0f;
    #pragma unroll
    for (int j = 0; j < 8; ++j) ps += (pv[j][0] + pv[j][1]) + (pv[j][2] + pv[j][3]);
    psum[pr][kqu][b] = ps;

    float acc[8];
    #pragma unroll
    for (int r = 0; r < 8; ++r) acc[r] = xacc[r];
    #pragma unroll
    for (int j = 0; j < 16; ++j) {
      #pragma unroll
      for (int u = 0; u < 4; ++u) {
        float v = hv[j][u];
        const float* wr = &Wh[kqu * 64 + 4 * j + u][0];
        #pragma unroll
        for (int r = 0; r < 8; ++r) acc[r] += v * wr[r];
      }
    }
    #pragma unroll
    for (int p = 0; p < 4; ++p) {
      red2[pr][kqu][p][b][0] = acc[2 * p];
      red2[pr][kqu][p][b][1] = acc[2 * p + 1];
    }
    __syncthreads();  // S1 — the ONLY barrier per step

    // ---- tail on waves 0..1 only (bit-identical replicas; waves 2..7
    // proceed straight to next-step x-matvec — no S2 barrier) ----
    if (kqu < 2) {
      float sc = ((psum[pr][0][b] + psum[pr][1][b]) + (psum[pr][2][b] + psum[pr][3][b]))
               + ((psum[pr][4][b] + psum[pr][5][b]) + (psum[pr][6][b] + psum[pr][7][b]));
      ins5v(sc, po0, po1, v0, v1, v2, v3, v4,
            qa0, qb0, qa1, qb1, qa2, qb2, qa3, qb3);
      mn = fminf(mn, sc);
      float delta = ((i + 1) <= 5 ? mn : v4) + EPSF;
      float w0 = fmaxf(v0 - delta, 0.0f);
      float w1 = fmaxf(v1 - delta, 0.0f);
      float w2 = fmaxf(v2 - delta, 0.0f);
      float w3 = fmaxf(v3 - delta, 0.0f);
      float inv = 1.0f / (w0 + w1 + w2 + w3 + EPSF);
      w0 *= inv; w1 *= inv; w2 *= inv; w3 *= inv;

      float G[8];
      #pragma unroll
      for (int r = 0; r < 8; ++r) G[r] = bias_r[r];
      #pragma unroll
      for (int q = 0; q < 8; ++q) {
        #pragma unroll
        for (int p = 0; p < 4; ++p) {
          G[2 * p]     += red2[pr][q][p][b][0];
          G[2 * p + 1] += red2[pr][q][p][b][1];
        }
      }

      float cn0 = sigf(G[2]) * cs0 + sigf(G[0]) * tanhf(G[4]);
      float hn0 = sigf(G[6]) * tanhf(cn0);
      float cn1 = sigf(G[3]) * cs1 + sigf(G[1]) * tanhf(G[5]);
      float hn1 = sigf(G[7]) * tanhf(cn1);
      cs0 = cn0; cs1 = cn1;

      float m0 = w0 * qa0 + w1 * qa1 + w2 * qa2 + w3 * qa3;  // registers, no gather
      float m1 = w0 * qb0 + w1 * qb1 + w2 * qb2 + w3 * qb3;
      float ho0 = hn0 + m0, ho1 = hn1 + m1;
      po0 = ho0; po1 = ho1;  // becomes mem[i+1] value for future insertions

      if (kqu == 0) {
        // wave 0: BOTH flag-gated planes, own-wave drain, then flag.
        // asm volatile + memory clobber chain => program-ordered.
        v2f hov; hov[0] = ho0; hov[1] = ho1;
        st_lic_f32x2(ws + MEM4_F + (unsigned)(i + 1) * 32768u + hoff0, hov);
        st_lic_f32(ws + PSUM4_F + (unsigned)(i + 1) * 16384u + (unsigned)(g >> 2) * 256u
                   + (unsigned)b * 4u + (unsigned)(g & 3),
                   tanhf(ho0) * wt20 + tanhf(ho1) * wt21);
        asm volatile("s_waitcnt vmcnt(0)" ::: "memory");
        if (tid == 0) st_lic_u32(&flags[g], (unsigned)(i + 1));
      } else {  // kqu == 1
        v2f mv; mv[0] = m0; mv[1] = m1;
        *(v2f*)(ws + MSEQ4_F + (unsigned)i * 32768u + hoff0) = mv;  // out_gemm-only
      }
    }

    // ---- overlap: x-part of NEXT step's matvec (static xT4) ----
    if (i + 1 < T_N) {
      const v4f* xp = (const v4f*)(ws + XT4_F) + (unsigned)(i + 1) * 4096u
                      + (unsigned)(kqu * 8) * 64u + b;
      v4f xv[8];
      #pragma unroll
      for (int j = 0; j < 8; ++j) xv[j] = xp[j * 64];
      #pragma unroll
      for (int r = 0; r < 8; ++r) xacc[r] = 0.0f;
      #pragma unroll
      for (int j = 0; j < 8; ++j) {
        #pragma unroll
        for (int u = 0; u < 4; ++u) {
          float v = xv[j][u];
          const float* wr = &Wx[kqu * 32 + 4 * j + u][0];
          #pragma unroll
          for (int r = 0; r < 8; ++r) xacc[r] += v * wr[r];
        }
      }
    }
  }
}

// out[t,b,c] = sum_d feats[t,d,b]*fcwT[d,c] + fc_b[c];
// feats h-half == mem4[t+1], m-half == mseq4[t] (packed [k4][b][4]).
__launch_bounds__(256, 4)
__global__ void out_gemm(const float* __restrict__ ws, const float* __restrict__ fc_b,
                         float* __restrict__ out) {
  __shared__ float fw[64][16];
  const int t = blockIdx.x >> 2, cg = blockIdx.x & 3;
  const int tid = threadIdx.x, b = tid & 63, cs = (tid >> 6) * 4;
  float acc[4] = {0.0f, 0.0f, 0.0f, 0.0f};
  const v4f* hsrc = (const v4f*)(ws + MEM4_F) + (unsigned)(t + 1) * 8192u + b;
  const v4f* msrc = (const v4f*)(ws + MSEQ4_F) + (unsigned)t * 8192u + b;
  for (int half = 0; half < 2; ++half) {
    const v4f* src = half ? msrc : hsrc;
    for (int dt = 0; dt < 512; dt += 64) {
      __syncthreads();
      for (int u = tid; u < 1024; u += 256) {
        int dd = u >> 4, cc = u & 15;
        fw[dd][cc] = ws[FCWT_F + (unsigned)(half * 512 + dt + dd) * 64u + cg * 16 + cc];
      }
      __syncthreads();
      #pragma unroll 4
      for (int j = 0; j < 16; ++j) {
        v4f f4 = src[(unsigned)(dt / 4 + j) * 64u];
        #pragma unroll
        for (int u = 0; u < 4; ++u) {
          float f = f4[u];
          const float* wr = &fw[4 * j + u][cs];
          #pragma unroll
          for (int c4 = 0; c4 < 4; ++c4) acc[c4] += f * wr[c4];
        }
      }
    }
  }
  float* op = out + ((unsigned)t * 64u + b) * 64u + cg * 16 + cs;
  #pragma unroll
  for (int c4 = 0; c4 < 4; ++c4) op[c4] = acc[c4] + fc_b[cg * 16 + cs + c4];
}

extern "C" void kernel_launch(void* const* d_in, const int* in_sizes, int n_in,
                              void* d_out, int out_size, void* d_ws, size_t ws_size,
                              hipStream_t stream) {
  const float* x    = (const float*)d_in[0];
  const float* W_ih = (const float*)d_in[1];
  const float* W_hh = (const float*)d_in[2];
  const float* b_ih = (const float*)d_in[3];
  const float* b_hh = (const float*)d_in[4];
  const float* w_t  = (const float*)d_in[5];
  const float* fc_w = (const float*)d_in[6];
  const float* fc_b = (const float*)d_in[7];
  float* out = (float*)d_out;
  float* ws  = (float*)d_ws;

  if (ws_size < (size_t)TOT_F * 4u) {
    poison_k<<<(out_size + 255) / 256, 256, 0, stream>>>(out, out_size);
    return;
  }

  hipMemsetAsync(ws + MEM4_F, 0, (size_t)32768u * 4u, stream);     // mem[0] = 0
  hipMemsetAsync(ws + PSUM4_F, 0, (size_t)16384u * 4u, stream);    // psum plane 0
  hipMemsetAsync(ws + FLAG_F, 0, 256u * 4u, stream);               // flags

  init_k<<<1040, 256, 0, stream>>>(x, fc_w, ws);
  lstm_main<<<256, 512, 0, stream>>>(W_ih, W_hh, b_ih, b_hh, w_t, ws);
  out_gemm<<<1024, 256, 0, stream>>>(ws, fc_b, out);
}

// Round 14
// 1697.042 us; speedup vs baseline: 1.4211x; 1.4211x over previous
//
#include <hip/hip_runtime.h>

// ---------------------------------------------------------------------------
// self_LSTM_sparse_attn — MI355X persistent-kernel, round 24 == R22/R18
// verbatim (session-best 1623.6us, restored as final state).
//
// R23 post-mortem (2412us, REGRESSION): removing S2 resurrected R9's spin
// storm. S2 was load-bearing as a SPIN THROTTLE: with it, waves 3..7 park
// silently in the HW barrier during the tail and reach the next S0 poll
// AFTER producers publish (polls exit ~immediately). Without it, ~1500
// waves arrive at S0 while producer wave-0s are still in their serial
// tail->store->drain->flag path, and their ld_lic_u32 spin loops hammer
// the LIC fabric in contention with the flag/data stores they await
// (VALUBusy 38->22.8%, +3.3us/step). Same signature as R9 (1790->2655).
//
// Final session map — all levers tested on hardware:
//   - weight delivery: LDS broadcast (1795) > scalar-SMEM (~2900) >
//     uniform-VMEM (4020). LDS optimal.
//   - 1024-thr/16-wave occupancy: dead — toolchain pins 64 VGPR regardless
//     of launch_bounds / waves_per_eu / LDS pressure (4 confirmations);
//     permanent spill storm.
//   - fp16 h-state: dead numerically (absmax 4.9 vs 0.4075; quantization
//     compounds through 256 recurrence steps + top-5 selection).
//   - split producer wait: dead — vmcnt(0) FIFO drains all older VMEM;
//     poll 2 force-drained half-1 data loads (stricter than single poll).
//   - S2 barrier removal: dead — spin-throttle role (above).
//   - tail gating to waves 0..2: WIN (+56us), banked here.
// Residual step time = serial LIC handoff + the throttle that keeps the
// protocol from self-contending; coupled, so overlap attempts regress.
// Not a HW roofline (VALUBusy 38%, HBM 3.5%) but a protocol plateau under
// the write-once/flag-gated invariant.
//
// Carried invariants (R5-R8-verified): cross-WG data write-once per step;
// cross-WG stores direct to LIC via sc0 sc1 (no fences anywhere); flag[g]
// stored only after the __syncthreads vmcnt-drain of g's plane stores;
// per-wave producer wait (wave kqu's psum slots AND mem dims both produced
// by WGs [32kqu,32kqu+32), lane polls flag[32kqu+(b&31)]).
// Algorithm (R2-R8-verified): s_h cancels in attention weights; w <=4-sparse;
// WG g owns h dims {2g,2g+1}; mem[i] == h_out(i-1); incremental top-5 with
// register-carried gather values (qa,qb).
// ---------------------------------------------------------------------------

#define T_N 256
#define B_N 64
#define I_N 256
#define H_N 512
#define C_N 64
#define EPSF 1e-7f

typedef float v4f __attribute__((ext_vector_type(4)));
typedef float v2f __attribute__((ext_vector_type(2)));

// ws layout (float offsets). Packed layouts: [..][k4][b][u] u=k&3.
#define XT4_F   0u          // [T][64][64][4]    x packed          (4,194,304)
#define MEM4_F  4194304u    // [T+1][128][64][4] h_out history     (8,421,376)
#define MSEQ4_F 12615680u   // [T][128][64][4]   m_seq             (8,388,608)
#define PSUM4_F 21004288u   // [T+1][64][64][4]  score partials, write-once (4,210,688)
#define FCWT_F  25214976u   // [2H][C] fc_w transposed             (65,536)
#define FLAG_F  25280512u   // [256] arrival flags, packed u32     (256)
#define TOT_F   25280768u

__device__ __forceinline__ float sigf(float x) { return 1.0f / (1.0f + expf(-x)); }

// direct-to-LIC (coherence point) ops — no fences needed anywhere.
__device__ __forceinline__ void st_lic_f32(float* p, float v) {
  asm volatile("global_store_dword %0, %1, off sc0 sc1" :: "v"(p), "v"(v) : "memory");
}
__device__ __forceinline__ void st_lic_f32x2(float* p, v2f v) {
  asm volatile("global_store_dwordx2 %0, %1, off sc0 sc1" :: "v"(p), "v"(v) : "memory");
}
__device__ __forceinline__ void st_lic_u32(unsigned* p, unsigned v) {
  asm volatile("global_store_dword %0, %1, off sc0 sc1" :: "v"(p), "v"(v) : "memory");
}
__device__ __forceinline__ unsigned ld_lic_u32(const unsigned* p) {
  unsigned r;
  asm volatile("global_load_dword %0, %1, off sc0 sc1\n\ts_waitcnt vmcnt(0)"
               : "=v"(r) : "v"(p) : "memory");
  return r;
}

// insert (s, a0, a1) into descending top-5; slots 0..3 carry values (qa,qb)
__device__ __forceinline__ void ins5v(float s, float a0, float a1,
    float& v0, float& v1, float& v2, float& v3, float& v4,
    float& qa0, float& qb0, float& qa1, float& qb1,
    float& qa2, float& qb2, float& qa3, float& qb3) {
  if (s > v4) {
    if (s > v0) {
      v4=v3; v3=v2; qa3=qa2; qb3=qb2; v2=v1; qa2=qa1; qb2=qb1;
      v1=v0; qa1=qa0; qb1=qb0; v0=s; qa0=a0; qb0=a1;
    } else if (s > v1) {
      v4=v3; v3=v2; qa3=qa2; qb3=qb2; v2=v1; qa2=qa1; qb2=qb1;
      v1=s; qa1=a0; qb1=a1;
    } else if (s > v2) {
      v4=v3; v3=v2; qa3=qa2; qb3=qb2; v2=s; qa2=a0; qb2=a1;
    } else if (s > v3) {
      v4=v3; v3=s; qa3=a0; qb3=a1;
    } else {
      v4=s;
    }
  }
}

__global__ void poison_k(float* out, int n) {
  int i = blockIdx.x * 256 + threadIdx.x;
  if (i < n) out[i] = __int_as_float(0x7fc00000);
}

// blocks 0..1023: x -> xT4 packed; blocks 1024..1039: fc_w -> fcwT[d][c]
__global__ void init_k(const float* __restrict__ x, const float* __restrict__ fc_w,
                       float* __restrict__ ws) {
  __shared__ float tile[64][65];
  const int blk = blockIdx.x, tid = threadIdx.x;
  if (blk < 1024) {
    const int t = blk >> 2, k0 = (blk & 3) * 64;
    for (int u = tid; u < 4096; u += 256) {
      int bb = u >> 6, kk = u & 63;
      tile[kk][bb] = x[((unsigned)t * 64u + bb) * 256u + k0 + kk];
    }
    __syncthreads();
    for (int u = tid; u < 4096; u += 256) {
      int kk = u >> 6, bb = u & 63;
      int k = k0 + kk;
      ws[XT4_F + (unsigned)t * 16384u + (unsigned)(k >> 2) * 256u
         + (unsigned)bb * 4u + (unsigned)(k & 3)] = tile[kk][bb];
    }
  } else {
    const int d0 = (blk - 1024) * 64;
    for (int u = tid; u < 4096; u += 256) {
      int cc = u >> 6, dd = u & 63;
      tile[dd][cc] = fc_w[(unsigned)cc * 1024u + d0 + dd];
    }
    __syncthreads();
    for (int u = tid; u < 4096; u += 256) {
      int dd = u >> 6, cc = u & 63;
      ws[FCWT_F + (unsigned)(d0 + dd) * 64u + cc] = tile[dd][cc];
    }
  }
}

__launch_bounds__(512, 1)
__global__ void lstm_main(const float* __restrict__ W_ih, const float* __restrict__ W_hh,
                          const float* __restrict__ b_ih, const float* __restrict__ b_hh,
                          const float* __restrict__ w_t, float* __restrict__ ws) {
  __shared__ float Wx[I_N][8];           // 8 KB  weight rows, LDS-resident
  __shared__ float Wh[H_N][8];           // 16 KB
  __shared__ float red2[8][4][B_N][2];   // 16 KB gate partials (row pairs)
  __shared__ float psum[8][B_N];         // 2 KB

  const int g = blockIdx.x;
  const int tid = threadIdx.x;
  const int b = tid & 63;
  const int kqu = __builtin_amdgcn_readfirstlane(tid >> 6);  // wave id 0..7

  unsigned int* flags = (unsigned int*)(ws + FLAG_F);

  // stage weights (resident all steps)
  for (int idx = tid; idx < 8 * I_N; idx += 512) {
    int rr = idx >> 8, k = idx & (I_N - 1);
    int grow = (rr >> 1) * H_N + 2 * g + (rr & 1);   // rr = gate*2 + jj
    Wx[k][rr] = W_ih[grow * I_N + k];
  }
  for (int idx = tid; idx < 8 * H_N; idx += 512) {
    int rr = idx >> 9, k = idx & (H_N - 1);
    int grow = (rr >> 1) * H_N + 2 * g + (rr & 1);
    Wh[k][rr] = W_hh[grow * H_N + k];
  }
  float bias_r[8];
  #pragma unroll
  for (int r = 0; r < 8; ++r) {
    int grow = (r >> 1) * H_N + 2 * g + (r & 1);
    bias_r[r] = b_ih[grow] + b_hh[grow];
  }
  const float wt20 = w_t[H_N + 2 * g];
  const float wt21 = w_t[H_N + 2 * g + 1];
  __syncthreads();

  // per-wave replicated state (bit-identical streams across tail waves 0..2)
  float cs0 = 0.0f, cs1 = 0.0f;                 // LSTM c-state
  float po0 = 0.0f, po1 = 0.0f;                 // ho(i-1) == mem[i] values (own dims)
  float v0 = -3e38f, v1 = -3e38f, v2 = -3e38f, v3 = -3e38f, v4 = -3e38f;
  float qa0 = 0, qb0 = 0, qa1 = 0, qb1 = 0, qa2 = 0, qb2 = 0, qa3 = 0, qb3 = 0;
  float mn = 3e38f;

  const unsigned hoff0 = (unsigned)(g >> 1) * 256u + (unsigned)b * 4u + (unsigned)((g & 1) * 2);

  // prologue: x-part of step 0's matvec (k-eighth per wave)
  float xacc[8];
  #pragma unroll
  for (int r = 0; r < 8; ++r) xacc[r] = 0.0f;
  {
    const v4f* xp = (const v4f*)(ws + XT4_F) + (unsigned)(kqu * 8) * 64u + b;
    v4f xv[8];
    #pragma unroll
    for (int j = 0; j < 8; ++j) xv[j] = xp[j * 64];
    #pragma unroll
    for (int j = 0; j < 8; ++j) {
      #pragma unroll
      for (int u = 0; u < 4; ++u) {
        float v = xv[j][u];
        const float* wr = &Wx[kqu * 32 + 4 * j + u][0];
        #pragma unroll
        for (int r = 0; r < 8; ++r) xacc[r] += v * wr[r];
      }
    }
  }

  for (int i = 0; i < T_N; ++i) {
    // ---- S0: per-wave producer wait. Wave kqu's psum slots AND mem dims
    // are both written exactly by WGs [32kqu, 32kqu+32). Single poll BEFORE
    // any data loads: its vmcnt(0) covers only the flag load (R21 lesson).
    if (i > 0) {
      const unsigned* fp = flags + (kqu * 32 + (b & 31));
      while (ld_lic_u32(fp) < (unsigned)i) __builtin_amdgcn_s_sleep(1);
    }

    // ---- Phase A: batched vector loads; weights broadcast from LDS ----
    v4f pv[8];
    {
      const v4f* pp = (const v4f*)(ws + PSUM4_F) + (unsigned)i * 4096u
                      + (unsigned)(kqu * 8) * 64u + b;
      #pragma unroll
      for (int j = 0; j < 8; ++j) pv[j] = pp[j * 64];
    }
    v4f hv[16];
    {
      const v4f* hp = (const v4f*)(ws + MEM4_F) + (unsigned)i * 8192u
                      + (unsigned)(kqu * 16) * 64u + b;  // mem[i] == h_out(i-1)
      #pragma unroll
      for (int j = 0; j < 16; ++j) hv[j] = hp[j * 64];
    }
    float ps = 0.0f;
    #pragma unroll
    for (int j = 0; j < 8; ++j) ps += (pv[j][0] + pv[j][1]) + (pv[j][2] + pv[j][3]);
    psum[kqu][b] = ps;

    float acc[8];
    #pragma unroll
    for (int r = 0; r < 8; ++r) acc[r] = xacc[r];
    #pragma unroll
    for (int j = 0; j < 16; ++j) {
      #pragma unroll
      for (int u = 0; u < 4; ++u) {
        float v = hv[j][u];
        const float* wr = &Wh[kqu * 64 + 4 * j + u][0];
        #pragma unroll
        for (int r = 0; r < 8; ++r) acc[r] += v * wr[r];
      }
    }
    #pragma unroll
    for (int p = 0; p < 4; ++p) {
      red2[kqu][p][b][0] = acc[2 * p];
      red2[kqu][p][b][1] = acc[2 * p + 1];
    }
    __syncthreads();  // S1

    // ---- tail on waves 0..2 only (bit-identical replicas; waves 3..7
    // park in the S2 HW barrier — no flag spinning, no LIC contention) ----
    if (kqu < 3) {
      float sc = ((psum[0][b] + psum[1][b]) + (psum[2][b] + psum[3][b]))
               + ((psum[4][b] + psum[5][b]) + (psum[6][b] + psum[7][b]));
      ins5v(sc, po0, po1, v0, v1, v2, v3, v4,
            qa0, qb0, qa1, qb1, qa2, qb2, qa3, qb3);
      mn = fminf(mn, sc);
      float delta = ((i + 1) <= 5 ? mn : v4) + EPSF;
      float w0 = fmaxf(v0 - delta, 0.0f);
      float w1 = fmaxf(v1 - delta, 0.0f);
      float w2 = fmaxf(v2 - delta, 0.0f);
      float w3 = fmaxf(v3 - delta, 0.0f);
      float inv = 1.0f / (w0 + w1 + w2 + w3 + EPSF);
      w0 *= inv; w1 *= inv; w2 *= inv; w3 *= inv;

      float G[8];
      #pragma unroll
      for (int r = 0; r < 8; ++r) G[r] = bias_r[r];
      #pragma unroll
      for (int q = 0; q < 8; ++q) {
        #pragma unroll
        for (int p = 0; p < 4; ++p) {
          G[2 * p]     += red2[q][p][b][0];
          G[2 * p + 1] += red2[q][p][b][1];
        }
      }

      float cn0 = sigf(G[2]) * cs0 + sigf(G[0]) * tanhf(G[4]);
      float hn0 = sigf(G[6]) * tanhf(cn0);
      float cn1 = sigf(G[3]) * cs1 + sigf(G[1]) * tanhf(G[5]);
      float hn1 = sigf(G[7]) * tanhf(cn1);
      cs0 = cn0; cs1 = cn1;

      float m0 = w0 * qa0 + w1 * qa1 + w2 * qa2 + w3 * qa3;  // registers, no gather
      float m1 = w0 * qb0 + w1 * qb1 + w2 * qb2 + w3 * qb3;
      float ho0 = hn0 + m0, ho1 = hn1 + m1;
      po0 = ho0; po1 = ho1;  // becomes mem[i+1] value for future insertions

      // disjoint store shares per wave
      if (kqu == 0) {
        v2f hov; hov[0] = ho0; hov[1] = ho1;
        st_lic_f32x2(ws + MEM4_F + (unsigned)(i + 1) * 32768u + hoff0, hov);
      } else if (kqu == 1) {
        v2f mv; mv[0] = m0; mv[1] = m1;
        *(v2f*)(ws + MSEQ4_F + (unsigned)i * 32768u + hoff0) = mv;  // out_gemm-only
      } else {  // kqu == 2
        st_lic_f32(ws + PSUM4_F + (unsigned)(i + 1) * 16384u + (unsigned)(g >> 2) * 256u
                   + (unsigned)b * 4u + (unsigned)(g & 3),
                   tanhf(ho0) * wt20 + tanhf(ho1) * wt21);
      }
    }
    __syncthreads();  // S2 — per-wave vmcnt(0) drain: all shares at LIC
    if (tid == 0) st_lic_u32(&flags[g], (unsigned)(i + 1));

    // ---- overlap: x-part of NEXT step's matvec (static xT4) ----
    if (i + 1 < T_N) {
      const v4f* xp = (const v4f*)(ws + XT4_F) + (unsigned)(i + 1) * 4096u
                      + (unsigned)(kqu * 8) * 64u + b;
      v4f xv[8];
      #pragma unroll
      for (int j = 0; j < 8; ++j) xv[j] = xp[j * 64];
      #pragma unroll
      for (int r = 0; r < 8; ++r) xacc[r] = 0.0f;
      #pragma unroll
      for (int j = 0; j < 8; ++j) {
        #pragma unroll
        for (int u = 0; u < 4; ++u) {
          float v = xv[j][u];
          const float* wr = &Wx[kqu * 32 + 4 * j + u][0];
          #pragma unroll
          for (int r = 0; r < 8; ++r) xacc[r] += v * wr[r];
        }
      }
    }
  }
}

// out[t,b,c] = sum_d feats[t,d,b]*fcwT[d,c] + fc_b[c];
// feats h-half == mem4[t+1], m-half == mseq4[t] (packed [k4][b][4]).
__launch_bounds__(256, 4)
__global__ void out_gemm(const float* __restrict__ ws, const float* __restrict__ fc_b,
                         float* __restrict__ out) {
  __shared__ float fw[64][16];
  const int t = blockIdx.x >> 2, cg = blockIdx.x & 3;
  const int tid = threadIdx.x, b = tid & 63, cs = (tid >> 6) * 4;
  float acc[4] = {0.0f, 0.0f, 0.0f, 0.0f};
  const v4f* hsrc = (const v4f*)(ws + MEM4_F) + (unsigned)(t + 1) * 8192u + b;
  const v4f* msrc = (const v4f*)(ws + MSEQ4_F) + (unsigned)t * 8192u + b;
  for (int half = 0; half < 2; ++half) {
    const v4f* src = half ? msrc : hsrc;
    for (int dt = 0; dt < 512; dt += 64) {
      __syncthreads();
      for (int u = tid; u < 1024; u += 256) {
        int dd = u >> 4, cc = u & 15;
        fw[dd][cc] = ws[FCWT_F + (unsigned)(half * 512 + dt + dd) * 64u + cg * 16 + cc];
      }
      __syncthreads();
      #pragma unroll 4
      for (int j = 0; j < 16; ++j) {
        v4f f4 = src[(unsigned)(dt / 4 + j) * 64u];
        #pragma unroll
        for (int u = 0; u < 4; ++u) {
          float f = f4[u];
          const float* wr = &fw[4 * j + u][cs];
          #pragma unroll
          for (int c4 = 0; c4 < 4; ++c4) acc[c4] += f * wr[c4];
        }
      }
    }
  }
  float* op = out + ((unsigned)t * 64u + b) * 64u + cg * 16 + cs;
  #pragma unroll
  for (int c4 = 0; c4 < 4; ++c4) op[c4] = acc[c4] + fc_b[cg * 16 + cs + c4];
}

extern "C" void kernel_launch(void* const* d_in, const int* in_sizes, int n_in,
                              void* d_out, int out_size, void* d_ws, size_t ws_size,
                              hipStream_t stream) {
  const float* x    = (const float*)d_in[0];
  const float* W_ih = (const float*)d_in[1];
  const float* W_hh = (const float*)d_in[2];
  const float* b_ih = (const float*)d_in[3];
  const float* b_hh = (const float*)d_in[4];
  const float* w_t  = (const float*)d_in[5];
  const float* fc_w = (const float*)d_in[6];
  const float* fc_b = (const float*)d_in[7];
  float* out = (float*)d_out;
  float* ws  = (float*)d_ws;

  if (ws_size < (size_t)TOT_F * 4u) {
    poison_k<<<(out_size + 255) / 256, 256, 0, stream>>>(out, out_size);
    return;
  }

  hipMemsetAsync(ws + MEM4_F, 0, (size_t)32768u * 4u, stream);     // mem[0] = 0
  hipMemsetAsync(ws + PSUM4_F, 0, (size_t)16384u * 4u, stream);    // psum plane 0
  hipMemsetAsync(ws + FLAG_F, 0, 256u * 4u, stream);               // flags

  init_k<<<1040, 256, 0, stream>>>(x, fc_w, ws);
  lstm_main<<<256, 512, 0, stream>>>(W_ih, W_hh, b_ih, b_hh, w_t, ws);
  out_gemm<<<1024, 256, 0, stream>>>(ws, fc_b, out);
}

// Round 15
// 1629.261 us; speedup vs baseline: 1.4802x; 1.0416x over previous
//
#include <hip/hip_runtime.h>

// ---------------------------------------------------------------------------
// self_LSTM_sparse_attn — MI355X persistent-kernel, FINAL (== R18/R22/R24).
// Best measured 1623.6us (R22); three runs of this exact kernel: 1638 /
// 1623.6 / 1697 -> noise band ~±4%. Session start was 1686us.
//
// Session conclusion — all structural levers hardware-tested:
//   - weight delivery: LDS broadcast (1795) > scalar-SMEM (~2900) >
//     uniform-VMEM (4020). LDS optimal for wave-uniform weight rows.
//   - 1024-thr/16-wave occupancy: dead — toolchain pins 64 VGPR regardless
//     of launch_bounds / waves_per_eu / LDS pressure (4 confirmations);
//     kernel needs ~90 -> permanent spill storm (WRITE_SIZE 3.4GB).
//   - fp16 h-state: dead numerically (absmax 4.9 vs 0.4075; quantization
//     compounds through 256 recurrence steps + top-5 selection flips).
//   - split producer wait: dead — vmcnt(0) is FIFO: poll 2 force-drains
//     the half-1 data loads (stricter serialization than a single poll).
//   - S2 barrier removal / flag-consolidation: dead — S2 is a load-bearing
//     SPIN THROTTLE. Without it ~1500 waves spin on ld_lic_u32 against the
//     very flag/data stores they await (R9: 2655us; R23: 2412us, same
//     signature: VALUBusy collapse). Even x-matvec placement after S2 is
//     load-bearing: it delays polls so they exit in ~1 iteration.
//   - tail gating to waves 0..2: WIN (+56us), banked here.
// Residual step time = serial LIC handoff (store-ack -> flag -> cross-XCD
// poll RTT -> data RTT) coupled to the throttle that prevents the protocol
// from self-contending. Not a HW roofline (VALUBusy 38%, HBM 3.5%) — a
// protocol plateau under the write-once/flag-gated coherence invariant.
//
// Carried invariants (R5-R8-verified): cross-WG data write-once per step;
// cross-WG stores direct to LIC via sc0 sc1 (no fences anywhere); flag[g]
// stored only after the __syncthreads vmcnt-drain of g's plane stores;
// per-wave producer wait (wave kqu's psum slots AND mem dims both produced
// by WGs [32kqu,32kqu+32), lane polls flag[32kqu+(b&31)]).
// Algorithm (R2-R8-verified): s_h cancels in attention weights; w <=4-sparse;
// WG g owns h dims {2g,2g+1}; mem[i] == h_out(i-1); incremental top-5 with
// register-carried gather values (qa,qb).
// ---------------------------------------------------------------------------

#define T_N 256
#define B_N 64
#define I_N 256
#define H_N 512
#define C_N 64
#define EPSF 1e-7f

typedef float v4f __attribute__((ext_vector_type(4)));
typedef float v2f __attribute__((ext_vector_type(2)));

// ws layout (float offsets). Packed layouts: [..][k4][b][u] u=k&3.
#define XT4_F   0u          // [T][64][64][4]    x packed          (4,194,304)
#define MEM4_F  4194304u    // [T+1][128][64][4] h_out history     (8,421,376)
#define MSEQ4_F 12615680u   // [T][128][64][4]   m_seq             (8,388,608)
#define PSUM4_F 21004288u   // [T+1][64][64][4]  score partials, write-once (4,210,688)
#define FCWT_F  25214976u   // [2H][C] fc_w transposed             (65,536)
#define FLAG_F  25280512u   // [256] arrival flags, packed u32     (256)
#define TOT_F   25280768u

__device__ __forceinline__ float sigf(float x) { return 1.0f / (1.0f + expf(-x)); }

// direct-to-LIC (coherence point) ops — no fences needed anywhere.
__device__ __forceinline__ void st_lic_f32(float* p, float v) {
  asm volatile("global_store_dword %0, %1, off sc0 sc1" :: "v"(p), "v"(v) : "memory");
}
__device__ __forceinline__ void st_lic_f32x2(float* p, v2f v) {
  asm volatile("global_store_dwordx2 %0, %1, off sc0 sc1" :: "v"(p), "v"(v) : "memory");
}
__device__ __forceinline__ void st_lic_u32(unsigned* p, unsigned v) {
  asm volatile("global_store_dword %0, %1, off sc0 sc1" :: "v"(p), "v"(v) : "memory");
}
__device__ __forceinline__ unsigned ld_lic_u32(const unsigned* p) {
  unsigned r;
  asm volatile("global_load_dword %0, %1, off sc0 sc1\n\ts_waitcnt vmcnt(0)"
               : "=v"(r) : "v"(p) : "memory");
  return r;
}

// insert (s, a0, a1) into descending top-5; slots 0..3 carry values (qa,qb)
__device__ __forceinline__ void ins5v(float s, float a0, float a1,
    float& v0, float& v1, float& v2, float& v3, float& v4,
    float& qa0, float& qb0, float& qa1, float& qb1,
    float& qa2, float& qb2, float& qa3, float& qb3) {
  if (s > v4) {
    if (s > v0) {
      v4=v3; v3=v2; qa3=qa2; qb3=qb2; v2=v1; qa2=qa1; qb2=qb1;
      v1=v0; qa1=qa0; qb1=qb0; v0=s; qa0=a0; qb0=a1;
    } else if (s > v1) {
      v4=v3; v3=v2; qa3=qa2; qb3=qb2; v2=v1; qa2=qa1; qb2=qb1;
      v1=s; qa1=a0; qb1=a1;
    } else if (s > v2) {
      v4=v3; v3=v2; qa3=qa2; qb3=qb2; v2=s; qa2=a0; qb2=a1;
    } else if (s > v3) {
      v4=v3; v3=s; qa3=a0; qb3=a1;
    } else {
      v4=s;
    }
  }
}

__global__ void poison_k(float* out, int n) {
  int i = blockIdx.x * 256 + threadIdx.x;
  if (i < n) out[i] = __int_as_float(0x7fc00000);
}

// blocks 0..1023: x -> xT4 packed; blocks 1024..1039: fc_w -> fcwT[d][c]
__global__ void init_k(const float* __restrict__ x, const float* __restrict__ fc_w,
                       float* __restrict__ ws) {
  __shared__ float tile[64][65];
  const int blk = blockIdx.x, tid = threadIdx.x;
  if (blk < 1024) {
    const int t = blk >> 2, k0 = (blk & 3) * 64;
    for (int u = tid; u < 4096; u += 256) {
      int bb = u >> 6, kk = u & 63;
      tile[kk][bb] = x[((unsigned)t * 64u + bb) * 256u + k0 + kk];
    }
    __syncthreads();
    for (int u = tid; u < 4096; u += 256) {
      int kk = u >> 6, bb = u & 63;
      int k = k0 + kk;
      ws[XT4_F + (unsigned)t * 16384u + (unsigned)(k >> 2) * 256u
         + (unsigned)bb * 4u + (unsigned)(k & 3)] = tile[kk][bb];
    }
  } else {
    const int d0 = (blk - 1024) * 64;
    for (int u = tid; u < 4096; u += 256) {
      int cc = u >> 6, dd = u & 63;
      tile[dd][cc] = fc_w[(unsigned)cc * 1024u + d0 + dd];
    }
    __syncthreads();
    for (int u = tid; u < 4096; u += 256) {
      int dd = u >> 6, cc = u & 63;
      ws[FCWT_F + (unsigned)(d0 + dd) * 64u + cc] = tile[dd][cc];
    }
  }
}

__launch_bounds__(512, 1)
__global__ void lstm_main(const float* __restrict__ W_ih, const float* __restrict__ W_hh,
                          const float* __restrict__ b_ih, const float* __restrict__ b_hh,
                          const float* __restrict__ w_t, float* __restrict__ ws) {
  __shared__ float Wx[I_N][8];           // 8 KB  weight rows, LDS-resident
  __shared__ float Wh[H_N][8];           // 16 KB
  __shared__ float red2[8][4][B_N][2];   // 16 KB gate partials (row pairs)
  __shared__ float psum[8][B_N];         // 2 KB

  const int g = blockIdx.x;
  const int tid = threadIdx.x;
  const int b = tid & 63;
  const int kqu = __builtin_amdgcn_readfirstlane(tid >> 6);  // wave id 0..7

  unsigned int* flags = (unsigned int*)(ws + FLAG_F);

  // stage weights (resident all steps)
  for (int idx = tid; idx < 8 * I_N; idx += 512) {
    int rr = idx >> 8, k = idx & (I_N - 1);
    int grow = (rr >> 1) * H_N + 2 * g + (rr & 1);   // rr = gate*2 + jj
    Wx[k][rr] = W_ih[grow * I_N + k];
  }
  for (int idx = tid; idx < 8 * H_N; idx += 512) {
    int rr = idx >> 9, k = idx & (H_N - 1);
    int grow = (rr >> 1) * H_N + 2 * g + (rr & 1);
    Wh[k][rr] = W_hh[grow * H_N + k];
  }
  float bias_r[8];
  #pragma unroll
  for (int r = 0; r < 8; ++r) {
    int grow = (r >> 1) * H_N + 2 * g + (r & 1);
    bias_r[r] = b_ih[grow] + b_hh[grow];
  }
  const float wt20 = w_t[H_N + 2 * g];
  const float wt21 = w_t[H_N + 2 * g + 1];
  __syncthreads();

  // per-wave replicated state (bit-identical streams across tail waves 0..2)
  float cs0 = 0.0f, cs1 = 0.0f;                 // LSTM c-state
  float po0 = 0.0f, po1 = 0.0f;                 // ho(i-1) == mem[i] values (own dims)
  float v0 = -3e38f, v1 = -3e38f, v2 = -3e38f, v3 = -3e38f, v4 = -3e38f;
  float qa0 = 0, qb0 = 0, qa1 = 0, qb1 = 0, qa2 = 0, qb2 = 0, qa3 = 0, qb3 = 0;
  float mn = 3e38f;

  const unsigned hoff0 = (unsigned)(g >> 1) * 256u + (unsigned)b * 4u + (unsigned)((g & 1) * 2);

  // prologue: x-part of step 0's matvec (k-eighth per wave)
  float xacc[8];
  #pragma unroll
  for (int r = 0; r < 8; ++r) xacc[r] = 0.0f;
  {
    const v4f* xp = (const v4f*)(ws + XT4_F) + (unsigned)(kqu * 8) * 64u + b;
    v4f xv[8];
    #pragma unroll
    for (int j = 0; j < 8; ++j) xv[j] = xp[j * 64];
    #pragma unroll
    for (int j = 0; j < 8; ++j) {
      #pragma unroll
      for (int u = 0; u < 4; ++u) {
        float v = xv[j][u];
        const float* wr = &Wx[kqu * 32 + 4 * j + u][0];
        #pragma unroll
        for (int r = 0; r < 8; ++r) xacc[r] += v * wr[r];
      }
    }
  }

  for (int i = 0; i < T_N; ++i) {
    // ---- S0: per-wave producer wait. Wave kqu's psum slots AND mem dims
    // are both written exactly by WGs [32kqu, 32kqu+32). Single poll BEFORE
    // any data loads: its vmcnt(0) covers only the flag load (R21 lesson).
    if (i > 0) {
      const unsigned* fp = flags + (kqu * 32 + (b & 31));
      while (ld_lic_u32(fp) < (unsigned)i) __builtin_amdgcn_s_sleep(1);
    }

    // ---- Phase A: batched vector loads; weights broadcast from LDS ----
    v4f pv[8];
    {
      const v4f* pp = (const v4f*)(ws + PSUM4_F) + (unsigned)i * 4096u
                      + (unsigned)(kqu * 8) * 64u + b;
      #pragma unroll
      for (int j = 0; j < 8; ++j) pv[j] = pp[j * 64];
    }
    v4f hv[16];
    {
      const v4f* hp = (const v4f*)(ws + MEM4_F) + (unsigned)i * 8192u
                      + (unsigned)(kqu * 16) * 64u + b;  // mem[i] == h_out(i-1)
      #pragma unroll
      for (int j = 0; j < 16; ++j) hv[j] = hp[j * 64];
    }
    float ps = 0.0f;
    #pragma unroll
    for (int j = 0; j < 8; ++j) ps += (pv[j][0] + pv[j][1]) + (pv[j][2] + pv[j][3]);
    psum[kqu][b] = ps;

    float acc[8];
    #pragma unroll
    for (int r = 0; r < 8; ++r) acc[r] = xacc[r];
    #pragma unroll
    for (int j = 0; j < 16; ++j) {
      #pragma unroll
      for (int u = 0; u < 4; ++u) {
        float v = hv[j][u];
        const float* wr = &Wh[kqu * 64 + 4 * j + u][0];
        #pragma unroll
        for (int r = 0; r < 8; ++r) acc[r] += v * wr[r];
      }
    }
    #pragma unroll
    for (int p = 0; p < 4; ++p) {
      red2[kqu][p][b][0] = acc[2 * p];
      red2[kqu][p][b][1] = acc[2 * p + 1];
    }
    __syncthreads();  // S1

    // ---- tail on waves 0..2 only (bit-identical replicas; waves 3..7
    // park in the S2 HW barrier — no flag spinning, no LIC contention) ----
    if (kqu < 3) {
      float sc = ((psum[0][b] + psum[1][b]) + (psum[2][b] + psum[3][b]))
               + ((psum[4][b] + psum[5][b]) + (psum[6][b] + psum[7][b]));
      ins5v(sc, po0, po1, v0, v1, v2, v3, v4,
            qa0, qb0, qa1, qb1, qa2, qb2, qa3, qb3);
      mn = fminf(mn, sc);
      float delta = ((i + 1) <= 5 ? mn : v4) + EPSF;
      float w0 = fmaxf(v0 - delta, 0.0f);
      float w1 = fmaxf(v1 - delta, 0.0f);
      float w2 = fmaxf(v2 - delta, 0.0f);
      float w3 = fmaxf(v3 - delta, 0.0f);
      float inv = 1.0f / (w0 + w1 + w2 + w3 + EPSF);
      w0 *= inv; w1 *= inv; w2 *= inv; w3 *= inv;

      float G[8];
      #pragma unroll
      for (int r = 0; r < 8; ++r) G[r] = bias_r[r];
      #pragma unroll
      for (int q = 0; q < 8; ++q) {
        #pragma unroll
        for (int p = 0; p < 4; ++p) {
          G[2 * p]     += red2[q][p][b][0];
          G[2 * p + 1] += red2[q][p][b][1];
        }
      }

      float cn0 = sigf(G[2]) * cs0 + sigf(G[0]) * tanhf(G[4]);
      float hn0 = sigf(G[6]) * tanhf(cn0);
      float cn1 = sigf(G[3]) * cs1 + sigf(G[1]) * tanhf(G[5]);
      float hn1 = sigf(G[7]) * tanhf(cn1);
      cs0 = cn0; cs1 = cn1;

      float m0 = w0 * qa0 + w1 * qa1 + w2 * qa2 + w3 * qa3;  // registers, no gather
      float m1 = w0 * qb0 + w1 * qb1 + w2 * qb2 + w3 * qb3;
      float ho0 = hn0 + m0, ho1 = hn1 + m1;
      po0 = ho0; po1 = ho1;  // becomes mem[i+1] value for future insertions

      // disjoint store shares per wave
      if (kqu == 0) {
        v2f hov; hov[0] = ho0; hov[1] = ho1;
        st_lic_f32x2(ws + MEM4_F + (unsigned)(i + 1) * 32768u + hoff0, hov);
      } else if (kqu == 1) {
        v2f mv; mv[0] = m0; mv[1] = m1;
        *(v2f*)(ws + MSEQ4_F + (unsigned)i * 32768u + hoff0) = mv;  // out_gemm-only
      } else {  // kqu == 2
        st_lic_f32(ws + PSUM4_F + (unsigned)(i + 1) * 16384u + (unsigned)(g >> 2) * 256u
                   + (unsigned)b * 4u + (unsigned)(g & 3),
                   tanhf(ho0) * wt20 + tanhf(ho1) * wt21);
      }
    }
    __syncthreads();  // S2 — per-wave vmcnt(0) drain: all shares at LIC
    if (tid == 0) st_lic_u32(&flags[g], (unsigned)(i + 1));

    // ---- overlap: x-part of NEXT step's matvec (static xT4) ----
    if (i + 1 < T_N) {
      const v4f* xp = (const v4f*)(ws + XT4_F) + (unsigned)(i + 1) * 4096u
                      + (unsigned)(kqu * 8) * 64u + b;
      v4f xv[8];
      #pragma unroll
      for (int j = 0; j < 8; ++j) xv[j] = xp[j * 64];
      #pragma unroll
      for (int r = 0; r < 8; ++r) xacc[r] = 0.0f;
      #pragma unroll
      for (int j = 0; j < 8; ++j) {
        #pragma unroll
        for (int u = 0; u < 4; ++u) {
          float v = xv[j][u];
          const float* wr = &Wx[kqu * 32 + 4 * j + u][0];
          #pragma unroll
          for (int r = 0; r < 8; ++r) xacc[r] += v * wr[r];
        }
      }
    }
  }
}

// out[t,b,c] = sum_d feats[t,d,b]*fcwT[d,c] + fc_b[c];
// feats h-half == mem4[t+1], m-half == mseq4[t] (packed [k4][b][4]).
__launch_bounds__(256, 4)
__global__ void out_gemm(const float* __restrict__ ws, const float* __restrict__ fc_b,
                         float* __restrict__ out) {
  __shared__ float fw[64][16];
  const int t = blockIdx.x >> 2, cg = blockIdx.x & 3;
  const int tid = threadIdx.x, b = tid & 63, cs = (tid >> 6) * 4;
  float acc[4] = {0.0f, 0.0f, 0.0f, 0.0f};
  const v4f* hsrc = (const v4f*)(ws + MEM4_F) + (unsigned)(t + 1) * 8192u + b;
  const v4f* msrc = (const v4f*)(ws + MSEQ4_F) + (unsigned)t * 8192u + b;
  for (int half = 0; half < 2; ++half) {
    const v4f* src = half ? msrc : hsrc;
    for (int dt = 0; dt < 512; dt += 64) {
      __syncthreads();
      for (int u = tid; u < 1024; u += 256) {
        int dd = u >> 4, cc = u & 15;
        fw[dd][cc] = ws[FCWT_F + (unsigned)(half * 512 + dt + dd) * 64u + cg * 16 + cc];
      }
      __syncthreads();
      #pragma unroll 4
      for (int j = 0; j < 16; ++j) {
        v4f f4 = src[(unsigned)(dt / 4 + j) * 64u];
        #pragma unroll
        for (int u = 0; u < 4; ++u) {
          float f = f4[u];
          const float* wr = &fw[4 * j + u][cs];
          #pragma unroll
          for (int c4 = 0; c4 < 4; ++c4) acc[c4] += f * wr[c4];
        }
      }
    }
  }
  float* op = out + ((unsigned)t * 64u + b) * 64u + cg * 16 + cs;
  #pragma unroll
  for (int c4 = 0; c4 < 4; ++c4) op[c4] = acc[c4] + fc_b[cg * 16 + cs + c4];
}

extern "C" void kernel_launch(void* const* d_in, const int* in_sizes, int n_in,
                              void* d_out, int out_size, void* d_ws, size_t ws_size,
                              hipStream_t stream) {
  const float* x    = (const float*)d_in[0];
  const float* W_ih = (const float*)d_in[1];
  const float* W_hh = (const float*)d_in[2];
  const float* b_ih = (const float*)d_in[3];
  const float* b_hh = (const float*)d_in[4];
  const float* w_t  = (const float*)d_in[5];
  const float* fc_w = (const float*)d_in[6];
  const float* fc_b = (const float*)d_in[7];
  float* out = (float*)d_out;
  float* ws  = (float*)d_ws;

  if (ws_size < (size_t)TOT_F * 4u) {
    poison_k<<<(out_size + 255) / 256, 256, 0, stream>>>(out, out_size);
    return;
  }

  hipMemsetAsync(ws + MEM4_F, 0, (size_t)32768u * 4u, stream);     // mem[0] = 0
  hipMemsetAsync(ws + PSUM4_F, 0, (size_t)16384u * 4u, stream);    // psum plane 0
  hipMemsetAsync(ws + FLAG_F, 0, 256u * 4u, stream);               // flags

  init_k<<<1040, 256, 0, stream>>>(x, fc_w, ws);
  lstm_main<<<256, 512, 0, stream>>>(W_ih, W_hh, b_ih, b_hh, w_t, ws);
  out_gemm<<<1024, 256, 0, stream>>>(ws, fc_b, out);
}